// Round 1
// baseline (707.601 us; speedup 1.0000x reference)
//
#include <hip/hip_runtime.h>
#include <hip/hip_bf16.h>

// GAT forward: N=8192 nodes, IN=512, HID=256, OUT=64.
// out = sigmoid( softmax_row( mask(leakyrelu(s1[i]+s2[j]), A) ) @ H1 @ Omega + beta )
// with H1 = X@W1+b1, s1 = H1@a1, s2 = H1@a2.
//
// Factorization: exp(e_ij) = A_ij * ( z>0 ? exp(s1_i)*exp(s2_j)
//                                        : exp(0.2 s1_i)*exp(0.2 s2_j) ),  z = s1_i+s2_j
// -> unnormalized W generated on the fly (bf16) feeding mfma_f32_16x16x32_bf16;
//    Z row-sums via shuffle+atomics; normalize + Omega matmul + sigmoid in epilogue.

typedef float f32x4 __attribute__((ext_vector_type(4)));
typedef short s16x8 __attribute__((ext_vector_type(8)));

#define NN 8192
#define INDIM 512
#define HIDD 256
#define OUTD 64

static __device__ __forceinline__ short f2bf(float x) {
    __hip_bfloat16 h = __float2bfloat16(x);
    return __builtin_bit_cast(short, h);
}

static __device__ __forceinline__ void split_bf(float x, short& hi, short& lo) {
    short h = f2bf(x);
    unsigned int hb = ((unsigned int)(unsigned short)h) << 16;
    float hf = __builtin_bit_cast(float, hb);
    hi = h;
    lo = f2bf(x - hf);
}

// ---------------- kernel 0: W1 (512x256 f32) -> W1^T hi/lo bf16 [256][512] -------------
__global__ void k_splitW1(const float* __restrict__ W1,
                          short* __restrict__ W1Thi, short* __restrict__ W1Tlo) {
    int t = blockIdx.x * 256 + threadIdx.x;   // t < 131072, t = n*512 + k
    int n = t >> 9;
    int k = t & 511;
    float x = W1[k * 256 + n];
    short hi, lo; split_bf(x, hi, lo);
    W1Thi[t] = hi;
    W1Tlo[t] = lo;
}

// ---------------- kernel 1: H1 = X@W1+b1 (split-bf16 MFMA, ~fp32 accuracy) ------------
// Also writes H1^T bf16 [256][8192] for the PV matmul, and fuses s1/s2/exp factors.
// Block 256 = 4 waves as (wm 2) x (wn 2): BM=32 rows, BN=256 cols. Grid 256.
__global__ void __launch_bounds__(256, 2)
k_h1(const float* __restrict__ X, const short* __restrict__ W1Thi,
     const short* __restrict__ W1Tlo, const float* __restrict__ b1,
     const float* __restrict__ avec, unsigned short* __restrict__ H1T,
     float* __restrict__ s1w, float* __restrict__ s2w,
     float* __restrict__ alw, float* __restrict__ bew,
     float* __restrict__ uw, float* __restrict__ vw) {
    __shared__ float s1p[2][32];
    __shared__ float s2p[2][32];
    const int tid = threadIdx.x;
    const int wave = tid >> 6, lane = tid & 63;
    const int wm = wave & 1, wn = wave >> 1;
    const int q = lane >> 4, m16 = lane & 15;
    const int i0 = blockIdx.x * 32;
    const int irow = i0 + wm * 16 + m16;      // A-frag row (m = lane&15)

    f32x4 zero4 = {0.f, 0.f, 0.f, 0.f};
    f32x4 acc[8];
#pragma unroll
    for (int nt = 0; nt < 8; ++nt) acc[nt] = zero4;

    const float* Xrow = X + (size_t)irow * INDIM;
    for (int kk = 0; kk < INDIM; kk += 32) {
        const int k0 = kk + q * 8;
        float4 xa = *(const float4*)(Xrow + k0);
        float4 xb = *(const float4*)(Xrow + k0 + 4);
        float xs[8] = {xa.x, xa.y, xa.z, xa.w, xb.x, xb.y, xb.z, xb.w};
        s16x8 ahi, alo;
#pragma unroll
        for (int j = 0; j < 8; ++j) { short h, l; split_bf(xs[j], h, l); ahi[j] = h; alo[j] = l; }
#pragma unroll
        for (int nt = 0; nt < 8; ++nt) {
            const int n = wn * 128 + nt * 16 + m16;
            s16x8 bhi = *(const s16x8*)(W1Thi + n * INDIM + k0);
            s16x8 blo = *(const s16x8*)(W1Tlo + n * INDIM + k0);
            acc[nt] = __builtin_amdgcn_mfma_f32_16x16x32_bf16(ahi, bhi, acc[nt], 0, 0, 0);
            acc[nt] = __builtin_amdgcn_mfma_f32_16x16x32_bf16(ahi, blo, acc[nt], 0, 0, 0);
            acc[nt] = __builtin_amdgcn_mfma_f32_16x16x32_bf16(alo, bhi, acc[nt], 0, 0, 0);
        }
    }

    // Epilogue: +b1, store H1^T bf16, fused s1/s2 partial dot products.
    float p1[4] = {0.f, 0.f, 0.f, 0.f};
    float p2[4] = {0.f, 0.f, 0.f, 0.f};
    const int rowbase = i0 + wm * 16 + q * 4;  // C rows: (lane>>4)*4 + r
#pragma unroll
    for (int nt = 0; nt < 8; ++nt) {
        const int col = wn * 128 + nt * 16 + m16;
        const float b1v = b1[col];
        const float a1v = avec[col];
        const float a2v = avec[HIDD + col];
        float v0 = acc[nt][0] + b1v;
        float v1 = acc[nt][1] + b1v;
        float v2 = acc[nt][2] + b1v;
        float v3 = acc[nt][3] + b1v;
        ushort4 us;
        us.x = (unsigned short)f2bf(v0);
        us.y = (unsigned short)f2bf(v1);
        us.z = (unsigned short)f2bf(v2);
        us.w = (unsigned short)f2bf(v3);
        *(ushort4*)(H1T + (size_t)col * NN + rowbase) = us;
        p1[0] += v0 * a1v; p1[1] += v1 * a1v; p1[2] += v2 * a1v; p1[3] += v3 * a1v;
        p2[0] += v0 * a2v; p2[1] += v1 * a2v; p2[2] += v2 * a2v; p2[3] += v3 * a2v;
    }
#pragma unroll
    for (int off = 1; off < 16; off <<= 1) {
#pragma unroll
        for (int r = 0; r < 4; ++r) {
            p1[r] += __shfl_xor(p1[r], off);
            p2[r] += __shfl_xor(p2[r], off);
        }
    }
    if (m16 == 0) {
#pragma unroll
        for (int r = 0; r < 4; ++r) {
            s1p[wn][wm * 16 + q * 4 + r] = p1[r];
            s2p[wn][wm * 16 + q * 4 + r] = p2[r];
        }
    }
    __syncthreads();
    if (tid < 32) {
        const int i = i0 + tid;
        float s1 = s1p[0][tid] + s1p[1][tid];
        float s2 = s2p[0][tid] + s2p[1][tid];
        s1w[i] = s1; s2w[i] = s2;
        alw[i] = expf(s1);
        bew[i] = expf(0.2f * s1);
        uw[i] = expf(s2);
        vw[i] = expf(0.2f * s2);
    }
}

// ---------------- kernel 3: H2acc = W @ H1 (bf16 MFMA), Z = rowsum(W) ------------------
// Grid 512 = (mb 128) x (Ksplit 4). Block 256 = 4 waves; wave = 16 rows x full N=256.
// W generated per-lane directly in A-fragment layout from adjacency stream.
__global__ void __launch_bounds__(256, 2)
k_attn(const int* __restrict__ A, const unsigned short* __restrict__ H1T,
       const float* __restrict__ s1w, const float* __restrict__ s2w,
       const float* __restrict__ alw, const float* __restrict__ bew,
       const float* __restrict__ uw, const float* __restrict__ vw,
       float* __restrict__ H2acc, float* __restrict__ Zw) {
    const int tid = threadIdx.x;
    const int wave = tid >> 6, lane = tid & 63;
    const int q = lane >> 4, m16 = lane & 15;
    const int mb = blockIdx.x & 127, ks = blockIdx.x >> 7;
    const int i = mb * 64 + wave * 16 + m16;
    const float s1i = s1w[i];
    const float al = alw[i];
    const float be = bew[i];
    const int* Arow = A + (size_t)i * NN;
    const unsigned short* Hb = H1T + m16 * NN;

    f32x4 zero4 = {0.f, 0.f, 0.f, 0.f};
    f32x4 acc[16];
#pragma unroll
    for (int nt = 0; nt < 16; ++nt) acc[nt] = zero4;
    float zacc = 0.f;

    const int kk0 = ks * 2048;
    for (int kk = kk0; kk < kk0 + 2048; kk += 32) {
        const int j0 = kk + q * 8;
        int4 A0 = *(const int4*)(Arow + j0);
        int4 A1 = *(const int4*)(Arow + j0 + 4);
        float4 u0 = *(const float4*)(uw + j0);
        float4 u1 = *(const float4*)(uw + j0 + 4);
        float4 v0 = *(const float4*)(vw + j0);
        float4 v1 = *(const float4*)(vw + j0 + 4);
        float4 t0 = *(const float4*)(s2w + j0);
        float4 t1 = *(const float4*)(s2w + j0 + 4);
        float wv[8];
        wv[0] = (A0.x > 0) ? ((s1i + t0.x > 0.f) ? al * u0.x : be * v0.x) : 0.f;
        wv[1] = (A0.y > 0) ? ((s1i + t0.y > 0.f) ? al * u0.y : be * v0.y) : 0.f;
        wv[2] = (A0.z > 0) ? ((s1i + t0.z > 0.f) ? al * u0.z : be * v0.z) : 0.f;
        wv[3] = (A0.w > 0) ? ((s1i + t0.w > 0.f) ? al * u0.w : be * v0.w) : 0.f;
        wv[4] = (A1.x > 0) ? ((s1i + t1.x > 0.f) ? al * u1.x : be * v1.x) : 0.f;
        wv[5] = (A1.y > 0) ? ((s1i + t1.y > 0.f) ? al * u1.y : be * v1.y) : 0.f;
        wv[6] = (A1.z > 0) ? ((s1i + t1.z > 0.f) ? al * u1.z : be * v1.z) : 0.f;
        wv[7] = (A1.w > 0) ? ((s1i + t1.w > 0.f) ? al * u1.w : be * v1.w) : 0.f;
        zacc += (wv[0] + wv[1] + wv[2] + wv[3]) + (wv[4] + wv[5] + wv[6] + wv[7]);
        s16x8 af;
#pragma unroll
        for (int j = 0; j < 8; ++j) af[j] = f2bf(wv[j]);
#pragma unroll
        for (int nt = 0; nt < 16; ++nt) {
            s16x8 bf = *(const s16x8*)(Hb + nt * 16 * NN + j0);
            acc[nt] = __builtin_amdgcn_mfma_f32_16x16x32_bf16(af, bf, acc[nt], 0, 0, 0);
        }
    }

    // Z row-sum: reduce over q groups (lanes ^16, ^32), one atomic per row per block.
    zacc += __shfl_xor(zacc, 16);
    zacc += __shfl_xor(zacc, 32);
    if (q == 0) atomicAdd(&Zw[i], zacc);

    const int rowbase = mb * 64 + wave * 16 + q * 4;
#pragma unroll
    for (int nt = 0; nt < 16; ++nt) {
        const int col = nt * 16 + m16;
#pragma unroll
        for (int r = 0; r < 4; ++r)
            atomicAdd(&H2acc[(size_t)(rowbase + r) * HIDD + col], acc[nt][r]);
    }
}

// ---------------- kernel 4: out = sigmoid((H2acc/Z) @ Omega + beta) --------------------
// Block 256 = 4 waves, 8 rows per wave (32 rows/block). Omega staged in LDS (64 KB).
__global__ void __launch_bounds__(256)
k_out(const float* __restrict__ H2acc, const float* __restrict__ Zw,
      const float* __restrict__ Omega, const float* __restrict__ beta,
      float* __restrict__ out) {
    __shared__ float om[HIDD * OUTD];  // 64 KB
    const int tid = threadIdx.x;
    for (int idx = tid; idx < HIDD * OUTD; idx += 256) om[idx] = Omega[idx];
    __syncthreads();
    const int wave = tid >> 6, o = tid & 63;
    const float bv = beta[o];
    for (int rr = 0; rr < 8; ++rr) {
        const int i = blockIdx.x * 32 + wave * 8 + rr;
        const float4* H2v = (const float4*)(H2acc + (size_t)i * HIDD);
        float acc = 0.f;
#pragma unroll 4
        for (int c4 = 0; c4 < 64; ++c4) {
            float4 h = H2v[c4];
            const int cb = c4 * 4;
            acc = fmaf(h.x, om[(cb + 0) * OUTD + o], acc);
            acc = fmaf(h.y, om[(cb + 1) * OUTD + o], acc);
            acc = fmaf(h.z, om[(cb + 2) * OUTD + o], acc);
            acc = fmaf(h.w, om[(cb + 3) * OUTD + o], acc);
        }
        const float zinv = 1.0f / Zw[i];
        const float logit = acc * zinv + bv;
        out[(size_t)i * OUTD + o] = 1.0f / (1.0f + expf(-logit));
    }
}

extern "C" void kernel_launch(void* const* d_in, const int* in_sizes, int n_in,
                              void* d_out, int out_size, void* d_ws, size_t ws_size,
                              hipStream_t stream) {
    const float* X     = (const float*)d_in[0];
    const int*   A     = (const int*)d_in[1];
    const float* W1    = (const float*)d_in[2];
    const float* b1    = (const float*)d_in[3];
    const float* avec  = (const float*)d_in[4];
    const float* Omega = (const float*)d_in[5];
    const float* beta  = (const float*)d_in[6];
    float* out = (float*)d_out;

    char* ws = (char*)d_ws;
    unsigned short* H1T = (unsigned short*)(ws + 0);        // 256*8192*2 = 4,194,304
    short* W1Thi = (short*)(ws + 4194304);                  // 262,144
    short* W1Tlo = (short*)(ws + 4456448);                  // 262,144
    float* s1w   = (float*)(ws + 4718592);                  // 32,768 each
    float* s2w   = (float*)(ws + 4751360);
    float* alw   = (float*)(ws + 4784128);
    float* bew   = (float*)(ws + 4816896);
    float* uw    = (float*)(ws + 4849664);
    float* vw    = (float*)(ws + 4882432);
    float* Zw    = (float*)(ws + 4915200);                  // 32,768
    float* H2acc = (float*)(ws + 4947968);                  // 8,388,608 (end 13,336,576)

    // Zero Z + H2acc (contiguous) — atomically accumulated in k_attn.
    hipMemsetAsync(Zw, 0, 32768 + 8388608, stream);

    k_splitW1<<<512, 256, 0, stream>>>(W1, W1Thi, W1Tlo);
    k_h1<<<256, 256, 0, stream>>>(X, W1Thi, W1Tlo, b1, avec, H1T,
                                  s1w, s2w, alw, bew, uw, vw);
    k_attn<<<512, 256, 0, stream>>>(A, H1T, s1w, s2w, alw, bew, uw, vw, H2acc, Zw);
    k_out<<<256, 256, 0, stream>>>(H2acc, Zw, Omega, beta, out);
}

// Round 2
// 543.873 us; speedup vs baseline: 1.3010x; 1.3010x over previous
//
#include <hip/hip_runtime.h>
#include <hip/hip_bf16.h>

// GAT forward: N=8192, IN=512, HID=256, OUT=64.
// exp-factorization + monotonicity: w_ij = A_ij * max( e^{s1_i} e^{s2_j},
//                                                      e^{0.2 s1_i} e^{0.2 s2_j} )
// k_attn: LDS-staged (global_load_lds w=16) bf16 MFMA over on-the-fly weights.

typedef float f32x4 __attribute__((ext_vector_type(4)));
typedef short s16x8 __attribute__((ext_vector_type(8)));

#define NN 8192
#define INDIM 512
#define HIDD 256
#define OUTD 64

static __device__ __forceinline__ short f2bf(float x) {
    __hip_bfloat16 h = __float2bfloat16(x);
    return __builtin_bit_cast(short, h);
}

static __device__ __forceinline__ void split_bf(float x, short& hi, short& lo) {
    short h = f2bf(x);
    unsigned int hb = ((unsigned int)(unsigned short)h) << 16;
    float hf = __builtin_bit_cast(float, hb);
    hi = h;
    lo = f2bf(x - hf);
}

// ---------------- kernel 0: W1 (512x256 f32) -> W1^T hi/lo bf16 [256][512] -------------
__global__ void k_splitW1(const float* __restrict__ W1,
                          short* __restrict__ W1Thi, short* __restrict__ W1Tlo) {
    int t = blockIdx.x * 256 + threadIdx.x;   // t = n*512 + k
    int n = t >> 9;
    int k = t & 511;
    float x = W1[k * 256 + n];
    short hi, lo; split_bf(x, hi, lo);
    W1Thi[t] = hi;
    W1Tlo[t] = lo;
}

// ---------------- kernel 1: H1 = X@W1+b1 (split-bf16 MFMA) ----------------------------
// Grid 512 x block 256: 16 rows/block, 4 waves = 4 col-groups of 64.
// Writes H1 in tile-contiguous bf16 layout H1TB[row/32][256 hid][32 row] and the
// per-node exp factors alw/bew (rows) and uvw interleaved (cols).
__global__ void __launch_bounds__(256, 2)
k_h1(const float* __restrict__ X, const short* __restrict__ W1Thi,
     const short* __restrict__ W1Tlo, const float* __restrict__ b1,
     const float* __restrict__ avec, unsigned short* __restrict__ H1TB,
     float* __restrict__ alw, float* __restrict__ bew, float* __restrict__ uvw) {
    __shared__ float s1p[4][16];
    __shared__ float s2p[4][16];
    const int tid = threadIdx.x;
    const int wn = tid >> 6, lane = tid & 63;
    const int q = lane >> 4, m16 = lane & 15;
    const int i0 = blockIdx.x * 16;
    const int irow = i0 + m16;

    f32x4 zero4 = {0.f, 0.f, 0.f, 0.f};
    f32x4 acc[4];
#pragma unroll
    for (int nt = 0; nt < 4; ++nt) acc[nt] = zero4;

    const float* Xrow = X + (size_t)irow * INDIM;
    for (int kk = 0; kk < INDIM; kk += 32) {
        const int k0 = kk + q * 8;
        float4 xa = *(const float4*)(Xrow + k0);
        float4 xb = *(const float4*)(Xrow + k0 + 4);
        float xs[8] = {xa.x, xa.y, xa.z, xa.w, xb.x, xb.y, xb.z, xb.w};
        s16x8 ahi, alo;
#pragma unroll
        for (int j = 0; j < 8; ++j) { short h, l; split_bf(xs[j], h, l); ahi[j] = h; alo[j] = l; }
#pragma unroll
        for (int nt = 0; nt < 4; ++nt) {
            const int n = wn * 64 + nt * 16 + m16;
            s16x8 bhi = *(const s16x8*)(W1Thi + n * INDIM + k0);
            s16x8 blo = *(const s16x8*)(W1Tlo + n * INDIM + k0);
            acc[nt] = __builtin_amdgcn_mfma_f32_16x16x32_bf16(ahi, bhi, acc[nt], 0, 0, 0);
            acc[nt] = __builtin_amdgcn_mfma_f32_16x16x32_bf16(ahi, blo, acc[nt], 0, 0, 0);
            acc[nt] = __builtin_amdgcn_mfma_f32_16x16x32_bf16(alo, bhi, acc[nt], 0, 0, 0);
        }
    }

    float p1[4] = {0.f, 0.f, 0.f, 0.f};
    float p2[4] = {0.f, 0.f, 0.f, 0.f};
    const int rowbase = i0 + q * 4;             // C rows: (lane>>4)*4 + r
    const int chunk = rowbase >> 5, win = rowbase & 31;
#pragma unroll
    for (int nt = 0; nt < 4; ++nt) {
        const int col = wn * 64 + nt * 16 + m16;
        const float b1v = b1[col];
        const float a1v = avec[col];
        const float a2v = avec[HIDD + col];
        float v0 = acc[nt][0] + b1v;
        float v1 = acc[nt][1] + b1v;
        float v2 = acc[nt][2] + b1v;
        float v3 = acc[nt][3] + b1v;
        ushort4 us;
        us.x = (unsigned short)f2bf(v0);
        us.y = (unsigned short)f2bf(v1);
        us.z = (unsigned short)f2bf(v2);
        us.w = (unsigned short)f2bf(v3);
        *(ushort4*)(H1TB + (size_t)chunk * 8192 + col * 32 + win) = us;
        p1[0] += v0 * a1v; p1[1] += v1 * a1v; p1[2] += v2 * a1v; p1[3] += v3 * a1v;
        p2[0] += v0 * a2v; p2[1] += v1 * a2v; p2[2] += v2 * a2v; p2[3] += v3 * a2v;
    }
#pragma unroll
    for (int off = 1; off < 16; off <<= 1) {
#pragma unroll
        for (int r = 0; r < 4; ++r) {
            p1[r] += __shfl_xor(p1[r], off);
            p2[r] += __shfl_xor(p2[r], off);
        }
    }
    if (m16 == 0) {
#pragma unroll
        for (int r = 0; r < 4; ++r) {
            s1p[wn][q * 4 + r] = p1[r];
            s2p[wn][q * 4 + r] = p2[r];
        }
    }
    __syncthreads();
    if (tid < 16) {
        const int i = i0 + tid;
        float s1 = s1p[0][tid] + s1p[1][tid] + s1p[2][tid] + s1p[3][tid];
        float s2 = s2p[0][tid] + s2p[1][tid] + s2p[2][tid] + s2p[3][tid];
        alw[i] = expf(s1);
        bew[i] = expf(0.2f * s1);
        uvw[2 * i]     = expf(s2);
        uvw[2 * i + 1] = expf(0.2f * s2);
    }
}

// ---------------- kernel 2: H2acc += W @ H1 (LDS-staged bf16 MFMA), Z = rowsum(W) ------
// Grid 1024 = mb(256, 32 rows) x ks(4, 2048 cols). Block 256 = 4 waves:
// wm = row-group (16 rows), wn = hid-group (128 cols). 16 KB LDS tile, 4 blocks/CU.
__global__ void __launch_bounds__(256, 4)
k_attn(const int* __restrict__ A, const unsigned short* __restrict__ H1TB,
       const float* __restrict__ alw, const float* __restrict__ bew,
       const float* __restrict__ uvw,
       float* __restrict__ H2acc, float* __restrict__ Zw) {
    __shared__ unsigned short tile[8192];   // 16 KB: [256 hid][32 j], 64 B per hid row

    const int tid = threadIdx.x;
    const int wave = tid >> 6, lane = tid & 63;
    const int q = lane >> 4, m16 = lane & 15;
    const int wm = wave & 1, wn = wave >> 1;
    const int mb = blockIdx.x & 255;
    const int ks = blockIdx.x >> 8;
    const int i = mb * 32 + wm * 16 + m16;
    const float al = alw[i], be = bew[i];

    // staging: thread t copies 4 x 16 B; global layout == LDS layout (tile-contiguous)
    const unsigned short* gp = H1TB + (size_t)ks * 64 * 8192 + tid * 8;
    __attribute__((address_space(3))) unsigned short* tl =
        (__attribute__((address_space(3))) unsigned short*)tile;

    const int* Ap = A + (size_t)i * NN + ks * 2048 + q * 8;
    const float* uvp = uvw + 2 * (ks * 2048 + q * 8);

    f32x4 zero4 = {0.f, 0.f, 0.f, 0.f};
    f32x4 acc[8];
#pragma unroll
    for (int nt = 0; nt < 8; ++nt) acc[nt] = zero4;
    float zacc = 0.f;

    for (int kk = 0; kk < 2048; kk += 32) {
#pragma unroll
        for (int c = 0; c < 4; ++c)
            __builtin_amdgcn_global_load_lds(
                (const __attribute__((address_space(1))) void*)(gp + c * 2048),
                (__attribute__((address_space(3))) void*)(tl + c * 2048 + tid * 8),
                16, 0, 0);
        gp += 8192;

        int4 A0 = *(const int4*)(Ap);
        int4 A1 = *(const int4*)(Ap + 4);
        float4 uv0 = *(const float4*)(uvp);
        float4 uv1 = *(const float4*)(uvp + 4);
        float4 uv2 = *(const float4*)(uvp + 8);
        float4 uv3 = *(const float4*)(uvp + 12);
        Ap += 32; uvp += 64;

        float wv[8];
        wv[0] = (A0.x > 0) ? fmaxf(al * uv0.x, be * uv0.y) : 0.f;
        wv[1] = (A0.y > 0) ? fmaxf(al * uv0.z, be * uv0.w) : 0.f;
        wv[2] = (A0.z > 0) ? fmaxf(al * uv1.x, be * uv1.y) : 0.f;
        wv[3] = (A0.w > 0) ? fmaxf(al * uv1.z, be * uv1.w) : 0.f;
        wv[4] = (A1.x > 0) ? fmaxf(al * uv2.x, be * uv2.y) : 0.f;
        wv[5] = (A1.y > 0) ? fmaxf(al * uv2.z, be * uv2.w) : 0.f;
        wv[6] = (A1.z > 0) ? fmaxf(al * uv3.x, be * uv3.y) : 0.f;
        wv[7] = (A1.w > 0) ? fmaxf(al * uv3.z, be * uv3.w) : 0.f;
        zacc += (wv[0] + wv[1] + wv[2] + wv[3]) + (wv[4] + wv[5] + wv[6] + wv[7]);
        s16x8 af;
#pragma unroll
        for (int j = 0; j < 8; ++j) af[j] = f2bf(wv[j]);

        __syncthreads();   // staging (vmcnt) drained by compiler before barrier
#pragma unroll
        for (int nt = 0; nt < 8; ++nt) {
            s16x8 bf = *(const s16x8*)(tile + (wn * 128 + nt * 16 + m16) * 32 + q * 8);
            acc[nt] = __builtin_amdgcn_mfma_f32_16x16x32_bf16(af, bf, acc[nt], 0, 0, 0);
        }
        __syncthreads();   // tile consumed; safe to overwrite next iter
    }

    // Z row-sum: reduce across q groups; one atomic per row (wn==0 waves only).
    zacc += __shfl_xor(zacc, 16);
    zacc += __shfl_xor(zacc, 32);
    if (wn == 0 && q == 0) atomicAdd(&Zw[i], zacc);

    const int rowbase = mb * 32 + wm * 16 + q * 4;
#pragma unroll
    for (int nt = 0; nt < 8; ++nt) {
        const int col = wn * 128 + nt * 16 + m16;
#pragma unroll
        for (int r = 0; r < 4; ++r)
            atomicAdd(&H2acc[(size_t)(rowbase + r) * HIDD + col], acc[nt][r]);
    }
}

// ---------------- kernel 3: out = sigmoid((H2acc/Z) @ Omega + beta) --------------------
__global__ void __launch_bounds__(256)
k_out(const float* __restrict__ H2acc, const float* __restrict__ Zw,
      const float* __restrict__ Omega, const float* __restrict__ beta,
      float* __restrict__ out) {
    __shared__ float om[HIDD * OUTD];  // 64 KB
    const int tid = threadIdx.x;
    for (int idx = tid; idx < HIDD * OUTD; idx += 256) om[idx] = Omega[idx];
    __syncthreads();
    const int wave = tid >> 6, o = tid & 63;
    const float bv = beta[o];
    for (int rr = 0; rr < 8; ++rr) {
        const int i = blockIdx.x * 32 + wave * 8 + rr;
        const float4* H2v = (const float4*)(H2acc + (size_t)i * HIDD);
        float acc = 0.f;
#pragma unroll 4
        for (int c4 = 0; c4 < 64; ++c4) {
            float4 h = H2v[c4];
            const int cb = c4 * 4;
            acc = fmaf(h.x, om[(cb + 0) * OUTD + o], acc);
            acc = fmaf(h.y, om[(cb + 1) * OUTD + o], acc);
            acc = fmaf(h.z, om[(cb + 2) * OUTD + o], acc);
            acc = fmaf(h.w, om[(cb + 3) * OUTD + o], acc);
        }
        const float zinv = 1.0f / Zw[i];
        const float logit = acc * zinv + bv;
        out[(size_t)i * OUTD + o] = 1.0f / (1.0f + expf(-logit));
    }
}

extern "C" void kernel_launch(void* const* d_in, const int* in_sizes, int n_in,
                              void* d_out, int out_size, void* d_ws, size_t ws_size,
                              hipStream_t stream) {
    const float* X     = (const float*)d_in[0];
    const int*   A     = (const int*)d_in[1];
    const float* W1    = (const float*)d_in[2];
    const float* b1    = (const float*)d_in[3];
    const float* avec  = (const float*)d_in[4];
    const float* Omega = (const float*)d_in[5];
    const float* beta  = (const float*)d_in[6];
    float* out = (float*)d_out;

    char* ws = (char*)d_ws;
    unsigned short* H1TB = (unsigned short*)(ws + 0);       // 4,194,304
    short* W1Thi = (short*)(ws + 4194304);                  // 262,144
    short* W1Tlo = (short*)(ws + 4456448);                  // 262,144
    float* alw   = (float*)(ws + 4718592);                  // 32,768
    float* bew   = (float*)(ws + 4751360);                  // 32,768
    float* uvw   = (float*)(ws + 4784128);                  // 65,536
    float* Zw    = (float*)(ws + 4849664);                  // 32,768
    float* H2acc = (float*)(ws + 4882432);                  // 8,388,608 (end 13,271,040)

    hipMemsetAsync(Zw, 0, 32768 + 8388608, stream);         // Zw + H2acc contiguous

    k_splitW1<<<512, 256, 0, stream>>>(W1, W1Thi, W1Tlo);
    k_h1<<<512, 256, 0, stream>>>(X, W1Thi, W1Tlo, b1, avec, H1TB, alw, bew, uvw);
    k_attn<<<1024, 256, 0, stream>>>(A, H1TB, alw, bew, uvw, H2acc, Zw);
    k_out<<<256, 256, 0, stream>>>(H2acc, Zw, Omega, beta, out);
}